// Round 3
// baseline (741.244 us; speedup 1.0000x reference)
//
#include <hip/hip_runtime.h>
#include <math.h>

#define NB 64
#define NN 4096
#define NF 256
#define NC 10
#define NSPLIT 16
#define CH 256            // rows per split
#define LW 263            // LDS tile pitch (floats) — odd → conflict-free transposed reads
#define EMPTYK 0xFFFFFFFFu

// ---------------------------------------------------------------- K0: class counts per batch
__global__ void k_counts(const int* __restrict__ Y, int* __restrict__ counts) {
  __shared__ int hist[NC];
  const int b = blockIdx.x;
  if (threadIdx.x < NC) hist[threadIdx.x] = 0;
  __syncthreads();
  for (int i = threadIdx.x; i < NN; i += blockDim.x) {
    int c = Y[b * NN + i];
    if (c >= 0 && c < NC) atomicAdd(&hist[c], 1);
  }
  __syncthreads();
  if (threadIdx.x < NC) counts[b * NC + threadIdx.x] = hist[threadIdx.x];
}

// ---------------------------------------------------------------- K1: streaming stats + transpose
__global__ __launch_bounds__(256) void k_stats(const float* __restrict__ X,
                                               const int* __restrict__ Y,
                                               unsigned* __restrict__ XT,
                                               float* __restrict__ P) {
  __shared__ unsigned ldsT[32 * LW];  // 33,664 B
  const int bi = blockIdx.x;
  const int b = bi >> 4, sp = bi & 15;
  const int t = threadIdx.x;
  const int w = t >> 6, l = t & 63;
  const int n0 = sp * CH;
  const float4* Xv = (const float4*)X;

  float s1[4] = {0, 0, 0, 0}, s2[4] = {0, 0, 0, 0}, sab[4] = {0, 0, 0, 0};
  float mab[4] = {0, 0, 0, 0}, nanc[4] = {0, 0, 0, 0};
  float cls[NC][4] = {};
  const int colbase = 4 * l + (l >> 3);

#define ADD4(c) do { cls[c][0]+=cv[0]; cls[c][1]+=cv[1]; cls[c][2]+=cv[2]; cls[c][3]+=cv[3]; } while(0)

  for (int tile = 0; tile < CH / 32; ++tile) {
#pragma unroll 4
    for (int it = 0; it < 8; ++it) {
      const int r = it * 4 + w;
      const int n = n0 + tile * 32 + r;
      float4 v4 = Xv[(size_t)(b * NN + n) * (NF / 4) + l];
      float v[4] = {v4.x, v4.y, v4.z, v4.w};
      float cv[4];
      unsigned ub[4];
#pragma unroll
      for (int q = 0; q < 4; ++q) {
        float c = v[q];
        if (c != c) { nanc[q] += 1.f; c = 0.f; }   // nan_to_num(nan=0)
        cv[q] = c;
        s1[q] += c;
        s2[q] = fmaf(c, c, s2[q]);
        float a = fabsf(c);
        sab[q] += a;
        mab[q] = fmaxf(mab[q], a);
        ub[q] = (c == 0.f) ? 0u : __float_as_uint(c);  // normalize -0 → +0 for bit-equality
      }
      const int ys = __builtin_amdgcn_readfirstlane(Y[b * NN + n]);  // wave-uniform
      switch (ys) {
        case 0: ADD4(0); break; case 1: ADD4(1); break;
        case 2: ADD4(2); break; case 3: ADD4(3); break;
        case 4: ADD4(4); break; case 5: ADD4(5); break;
        case 6: ADD4(6); break; case 7: ADD4(7); break;
        case 8: ADD4(8); break; case 9: ADD4(9); break;
        default: break;
      }
      const int lb = r * LW + colbase;
      ldsT[lb + 0] = ub[0]; ldsT[lb + 1] = ub[1];
      ldsT[lb + 2] = ub[2]; ldsT[lb + 3] = ub[3];
    }
    __syncthreads();
    // transposed write-out: each thread packs 4 rows of one feature into a dwordx4 store.
#pragma unroll
    for (int j = 0; j < 8; ++j) {
      const int idx = t + 256 * j;
      const int f = idx >> 3, rr4 = idx & 7;
      const int fo = f + (f >> 5);
      uint4 o;
      o.x = ldsT[(rr4 * 4 + 0) * LW + fo];
      o.y = ldsT[(rr4 * 4 + 1) * LW + fo];
      o.z = ldsT[(rr4 * 4 + 2) * LW + fo];
      o.w = ldsT[(rr4 * 4 + 3) * LW + fo];
      ((uint4*)(XT + (size_t)(b * NF + f) * NN + n0 + tile * 32))[rr4] = o;
    }
    __syncthreads();
  }

  // cross-wave reduction of the 4 row-phases into LDS [256 features][16 stats]
  float* red = (float*)ldsT;
  for (int ph = 0; ph < 4; ++ph) {
    if (w == ph) {
#pragma unroll
      for (int ff = 0; ff < 4; ++ff) {
        const int f = 4 * l + ff;
        float vals[16];
        vals[0] = s1[ff]; vals[1] = s2[ff]; vals[2] = sab[ff];
        vals[3] = mab[ff]; vals[4] = nanc[ff];
#pragma unroll
        for (int c = 0; c < NC; ++c) vals[5 + c] = cls[c][ff];
        vals[15] = 0.f;
        if (ph == 0) {
#pragma unroll
          for (int s = 0; s < 16; ++s) red[f * 16 + s] = vals[s];
        } else {
          red[f * 16 + 0] += vals[0];
          red[f * 16 + 1] += vals[1];
          red[f * 16 + 2] += vals[2];
          red[f * 16 + 3] = fmaxf(red[f * 16 + 3], vals[3]);
          red[f * 16 + 4] += vals[4];
#pragma unroll
          for (int c = 0; c < NC; ++c) red[f * 16 + 5 + c] += vals[5 + c];
        }
      }
    }
    __syncthreads();
  }
  float4* Pv = (float4*)(P + ((size_t)(b * NSPLIT + sp) * NF + t) * 16);
  const float4* rv = (const float4*)(red + t * 16);
  Pv[0] = rv[0]; Pv[1] = rv[1]; Pv[2] = rv[2]; Pv[3] = rv[3];
#undef ADD4
}

// ---------------------------------------------------------------- K3: exact distinct count per column
// v3: fully batched probing. Round 0 issues all 16 direct-CAS inserts as one batch;
// every later round re-issues ALL still-pending (lane,q) probes as one batch (single
// waitcnt per round), so total latency = max probe-chain × ~150cyc instead of
// Σ_q max_lanes(chain_q). Double-hashed odd step kills linear-probe clustering.
__global__ __launch_bounds__(256) void k_uniq(const unsigned* __restrict__ XT,
                                              unsigned* __restrict__ uniq) {
  __shared__ unsigned tab[8192];   // 32,768 B exactly → 5 blocks/CU
  const int t = threadIdx.x;
  const size_t base = (size_t)blockIdx.x * NN;

  // issue global loads first so they overlap table init
  const uint4* Xv = (const uint4*)(XT + base);
  uint4 kv0 = Xv[t], kv1 = Xv[256 + t], kv2 = Xv[512 + t], kv3 = Xv[768 + t];

  uint4* tv = (uint4*)tab;
  const uint4 e4 = make_uint4(EMPTYK, EMPTYK, EMPTYK, EMPTYK);
#pragma unroll
  for (int i = 0; i < 8; ++i) tv[t + 256 * i] = e4;

  unsigned key[16] = {kv0.x, kv0.y, kv0.z, kv0.w, kv1.x, kv1.y, kv1.z, kv1.w,
                      kv2.x, kv2.y, kv2.z, kv2.w, kv3.x, kv3.y, kv3.z, kv3.w};
  unsigned h[16], old[16];
#pragma unroll
  for (int q = 0; q < 16; ++q) h[q] = (key[q] * 2654435761u) >> 19;  // 13 bits
  __syncthreads();

#pragma unroll
  for (int q = 0; q < 16; ++q) old[q] = atomicCAS(&tab[h[q]], EMPTYK, key[q]);

  int cnt = 0;
  unsigned pend = 0;
#pragma unroll
  for (int q = 0; q < 16; ++q) {
    if (old[q] == EMPTYK) cnt++;                      // claimed a fresh slot
    else if (old[q] != key[q]) pend |= (1u << q);     // occupied by other key → probe
    // else: duplicate value, done
  }

  while (pend) {                                      // wave-divergent; rounds = max chain
#pragma unroll
    for (int q = 0; q < 16; ++q)
      if (pend & (1u << q)) {
        const unsigned stp = ((key[q] * 0x85EBCA6Bu) >> 20) | 1u;  // odd → full cycle mod 8192
        h[q] = (h[q] + stp) & 8191;
        old[q] = atomicCAS(&tab[h[q]], EMPTYK, key[q]);
      }
#pragma unroll
    for (int q = 0; q < 16; ++q)
      if (pend & (1u << q)) {
        if (old[q] == EMPTYK) { cnt++; pend &= ~(1u << q); }
        else if (old[q] == key[q]) pend &= ~(1u << q);
      }
  }

  for (int off = 32; off; off >>= 1) cnt += __shfl_down(cnt, off, 64);
  __syncthreads();                  // all inserts done; table memory now reusable
  if ((t & 63) == 0) tab[t >> 6] = (unsigned)cnt;
  __syncthreads();
  if (t == 0) uniq[blockIdx.x] = tab[0] + tab[1] + tab[2] + tab[3];
}

// ---------------------------------------------------------------- K2: reduce partials → 6 stats
__global__ void k_finalize(const float* __restrict__ P, const int* __restrict__ counts,
                           const unsigned* __restrict__ uniq, float* __restrict__ stats6) {
  const int col = blockIdx.x * 256 + threadIdx.x;  // 16384 columns
  const int b = col >> 8;
  const int f = col & 255;
  float acc[16];
#pragma unroll
  for (int i = 0; i < 16; ++i) acc[i] = 0.f;
  for (int sp = 0; sp < NSPLIT; ++sp) {
    const float4* p4 = (const float4*)(P + ((size_t)(b * NSPLIT + sp) * NF + f) * 16);
    float4 A = p4[0], B4 = p4[1], C4 = p4[2], D4 = p4[3];
    acc[0] += A.x; acc[1] += A.y; acc[2] += A.z; acc[3] = fmaxf(acc[3], A.w);
    acc[4] += B4.x; acc[5] += B4.y; acc[6] += B4.z; acc[7] += B4.w;
    acc[8] += C4.x; acc[9] += C4.y; acc[10] += C4.z; acc[11] += C4.w;
    acc[12] += D4.x; acc[13] += D4.y; acc[14] += D4.z;
  }
  const float invN = 1.f / (float)NN;
  const float mean = acc[0] * invN;
  float var = acc[1] * invN - mean * mean;
  if (var < 0.f) var = 0.f;
  const float meanabs = acc[2] * invN;
  const float maxabs = acc[3];
  const float miss = acc[4] * invN;
  const float uratio = (float)uniq[col] * invN;
  float btw = 0.f;
#pragma unroll
  for (int c = 0; c < NC; ++c) {
    float cntc = (float)counts[b * NC + c];
    float m = acc[5 + c] / fmaxf(cntc, 1.f);
    float d = m - mean;
    btw = fmaf(cntc * d, d, btw);
  }
  btw *= invN;  // counts.sum() == N
  const float target = btw / fmaxf(var, 1e-6f);
  float st[6] = {target, miss, uratio, var, meanabs, maxabs};
#pragma unroll
  for (int i = 0; i < 6; ++i)
    if (!(fabsf(st[i]) <= 3.4028235e38f)) st[i] = 0.f;  // nan_to_num(nan/±inf → 0)
#pragma unroll
  for (int i = 0; i < 6; ++i) stats6[(size_t)col * 6 + i] = st[i];
}

// ---------------------------------------------------------------- K4: MLP  gelu(stats@W1+b1)@W2+b2
__global__ __launch_bounds__(256) void k_mlp(const float* __restrict__ stats6,
                                             const float* __restrict__ W1,
                                             const float* __restrict__ b1,
                                             const float* __restrict__ W2,
                                             const float* __restrict__ b2,
                                             float* __restrict__ out) {
  __shared__ float w1s[6 * 64];
  __shared__ float b1s[64];
  __shared__ float w2s[64 * 128];
  __shared__ float b2s[128];
  __shared__ float sts[32 * 6];
  __shared__ float hs[64 * 36];  // pitch 36 keeps float4 reads 16B-aligned
  const int t = threadIdx.x;
  const int cb0 = blockIdx.x * 32;
  for (int i = t; i < 96; i += 256) ((float4*)w1s)[i] = ((const float4*)W1)[i];
  if (t < 64) b1s[t] = b1[t];
  for (int i = t; i < 2048; i += 256) ((float4*)w2s)[i] = ((const float4*)W2)[i];
  if (t < 128) b2s[t] = b2[t];
  if (t < 48) ((float4*)sts)[t] = ((const float4*)(stats6 + (size_t)cb0 * 6))[t];
  __syncthreads();

  const int k = t & 63, cg = t >> 6;
#pragma unroll
  for (int cc = 0; cc < 8; ++cc) {
    const int col = cg + 4 * cc;
    float pre = b1s[k];
#pragma unroll
    for (int s = 0; s < 6; ++s) pre = fmaf(sts[col * 6 + s], w1s[s * 64 + k], pre);
    const float h = 0.5f * pre * (1.f + erff(pre * 0.70710678118654752f));  // exact gelu
    hs[k * 36 + col] = h;
  }
  __syncthreads();

  const int j4 = (t & 31) * 4, c4 = (t >> 5) * 4;
  float4 a[4];
  const float4 bj = *(const float4*)&b2s[j4];
  a[0] = bj; a[1] = bj; a[2] = bj; a[3] = bj;
  for (int kk = 0; kk < 64; ++kk) {
    const float4 wv = *(const float4*)&w2s[kk * 128 + j4];
    const float4 hv = *(const float4*)&hs[kk * 36 + c4];
    const float hc[4] = {hv.x, hv.y, hv.z, hv.w};
#pragma unroll
    for (int ci = 0; ci < 4; ++ci) {
      a[ci].x = fmaf(hc[ci], wv.x, a[ci].x);
      a[ci].y = fmaf(hc[ci], wv.y, a[ci].y);
      a[ci].z = fmaf(hc[ci], wv.z, a[ci].z);
      a[ci].w = fmaf(hc[ci], wv.w, a[ci].w);
    }
  }
#pragma unroll
  for (int ci = 0; ci < 4; ++ci) {
    const int col = cb0 + c4 + ci;
    *(float4*)&out[(size_t)col * 128 + j4] = a[ci];
  }
}

// ---------------------------------------------------------------- launch
extern "C" void kernel_launch(void* const* d_in, const int* in_sizes, int n_in,
                              void* d_out, int out_size, void* d_ws, size_t ws_size,
                              hipStream_t stream) {
  const float* X = (const float*)d_in[0];
  const int* Y = (const int*)d_in[1];
  const float* W1 = (const float*)d_in[2];
  const float* b1 = (const float*)d_in[3];
  const float* W2 = (const float*)d_in[4];
  const float* b2 = (const float*)d_in[5];
  float* out = (float*)d_out;

  // workspace layout (needs ~272.4 MiB)
  char* w = (char*)d_ws;
  unsigned* XT = (unsigned*)w;                          // 268,435,456 B  [B,F,N] cleaned bit patterns
  float* P = (float*)(w + 268435456ull);                //  16,777,216 B  partial stats [B,S,F,16]
  float* stats6 = (float*)(w + 285212672ull);           //     393,216 B  [16384,6]
  int* counts = (int*)(w + 285605888ull);               //       2,560 B  [B,10]
  unsigned* uniq = (unsigned*)(w + 285608448ull);       //      65,536 B  [16384]

  k_counts<<<NB, 256, 0, stream>>>(Y, counts);
  k_stats<<<NB * NSPLIT, 256, 0, stream>>>(X, Y, XT, P);
  k_uniq<<<NB * NF, 256, 0, stream>>>(XT, uniq);
  k_finalize<<<64, 256, 0, stream>>>(P, counts, uniq, stats6);
  k_mlp<<<512, 256, 0, stream>>>(stats6, W1, b1, W2, b2, out);
}

// Round 4
// 653.473 us; speedup vs baseline: 1.1343x; 1.1343x over previous
//
#include <hip/hip_runtime.h>
#include <math.h>

#define NB 64
#define NN 4096
#define NF 256
#define NC 10
#define NSPLIT 16
#define CH 256            // rows per split
#define LW 263            // LDS tile pitch (floats) — odd → conflict-free transposed reads
#define EMPTYK 0xFFFFFFFFu

// ---------------------------------------------------------------- K0: class counts per batch
__global__ void k_counts(const int* __restrict__ Y, int* __restrict__ counts) {
  __shared__ int hist[NC];
  const int b = blockIdx.x;
  if (threadIdx.x < NC) hist[threadIdx.x] = 0;
  __syncthreads();
  for (int i = threadIdx.x; i < NN; i += blockDim.x) {
    int c = Y[b * NN + i];
    if (c >= 0 && c < NC) atomicAdd(&hist[c], 1);
  }
  __syncthreads();
  if (threadIdx.x < NC) counts[b * NC + threadIdx.x] = hist[threadIdx.x];
}

// ---------------------------------------------------------------- K1: streaming stats + transpose
__global__ __launch_bounds__(256) void k_stats(const float* __restrict__ X,
                                               const int* __restrict__ Y,
                                               unsigned* __restrict__ XT,
                                               float* __restrict__ P) {
  __shared__ unsigned ldsT[32 * LW];  // 33,664 B
  const int bi = blockIdx.x;
  const int b = bi >> 4, sp = bi & 15;
  const int t = threadIdx.x;
  const int w = t >> 6, l = t & 63;
  const int n0 = sp * CH;
  const float4* Xv = (const float4*)X;

  float s1[4] = {0, 0, 0, 0}, s2[4] = {0, 0, 0, 0}, sab[4] = {0, 0, 0, 0};
  float mab[4] = {0, 0, 0, 0}, nanc[4] = {0, 0, 0, 0};
  float cls[NC][4] = {};
  const int colbase = 4 * l + (l >> 3);

#define ADD4(c) do { cls[c][0]+=cv[0]; cls[c][1]+=cv[1]; cls[c][2]+=cv[2]; cls[c][3]+=cv[3]; } while(0)

  for (int tile = 0; tile < CH / 32; ++tile) {
#pragma unroll 4
    for (int it = 0; it < 8; ++it) {
      const int r = it * 4 + w;
      const int n = n0 + tile * 32 + r;
      float4 v4 = Xv[(size_t)(b * NN + n) * (NF / 4) + l];
      float v[4] = {v4.x, v4.y, v4.z, v4.w};
      float cv[4];
      unsigned ub[4];
#pragma unroll
      for (int q = 0; q < 4; ++q) {
        float c = v[q];
        if (c != c) { nanc[q] += 1.f; c = 0.f; }   // nan_to_num(nan=0)
        cv[q] = c;
        s1[q] += c;
        s2[q] = fmaf(c, c, s2[q]);
        float a = fabsf(c);
        sab[q] += a;
        mab[q] = fmaxf(mab[q], a);
        ub[q] = (c == 0.f) ? 0u : __float_as_uint(c);  // normalize -0 → +0 for bit-equality
      }
      const int ys = __builtin_amdgcn_readfirstlane(Y[b * NN + n]);  // wave-uniform
      switch (ys) {
        case 0: ADD4(0); break; case 1: ADD4(1); break;
        case 2: ADD4(2); break; case 3: ADD4(3); break;
        case 4: ADD4(4); break; case 5: ADD4(5); break;
        case 6: ADD4(6); break; case 7: ADD4(7); break;
        case 8: ADD4(8); break; case 9: ADD4(9); break;
        default: break;
      }
      const int lb = r * LW + colbase;
      ldsT[lb + 0] = ub[0]; ldsT[lb + 1] = ub[1];
      ldsT[lb + 2] = ub[2]; ldsT[lb + 3] = ub[3];
    }
    __syncthreads();
    // transposed write-out: each thread packs 4 rows of one feature into a dwordx4 store.
#pragma unroll
    for (int j = 0; j < 8; ++j) {
      const int idx = t + 256 * j;
      const int f = idx >> 3, rr4 = idx & 7;
      const int fo = f + (f >> 5);
      uint4 o;
      o.x = ldsT[(rr4 * 4 + 0) * LW + fo];
      o.y = ldsT[(rr4 * 4 + 1) * LW + fo];
      o.z = ldsT[(rr4 * 4 + 2) * LW + fo];
      o.w = ldsT[(rr4 * 4 + 3) * LW + fo];
      ((uint4*)(XT + (size_t)(b * NF + f) * NN + n0 + tile * 32))[rr4] = o;
    }
    __syncthreads();
  }

  // cross-wave reduction of the 4 row-phases into LDS [256 features][16 stats]
  float* red = (float*)ldsT;
  for (int ph = 0; ph < 4; ++ph) {
    if (w == ph) {
#pragma unroll
      for (int ff = 0; ff < 4; ++ff) {
        const int f = 4 * l + ff;
        float vals[16];
        vals[0] = s1[ff]; vals[1] = s2[ff]; vals[2] = sab[ff];
        vals[3] = mab[ff]; vals[4] = nanc[ff];
#pragma unroll
        for (int c = 0; c < NC; ++c) vals[5 + c] = cls[c][ff];
        vals[15] = 0.f;
        if (ph == 0) {
#pragma unroll
          for (int s = 0; s < 16; ++s) red[f * 16 + s] = vals[s];
        } else {
          red[f * 16 + 0] += vals[0];
          red[f * 16 + 1] += vals[1];
          red[f * 16 + 2] += vals[2];
          red[f * 16 + 3] = fmaxf(red[f * 16 + 3], vals[3]);
          red[f * 16 + 4] += vals[4];
#pragma unroll
          for (int c = 0; c < NC; ++c) red[f * 16 + 5 + c] += vals[5 + c];
        }
      }
    }
    __syncthreads();
  }
  float4* Pv = (float4*)(P + ((size_t)(b * NSPLIT + sp) * NF + t) * 16);
  const float4* rv = (const float4*)(red + t * 16);
  Pv[0] = rv[0]; Pv[1] = rv[1]; Pv[2] = rv[2]; Pv[3] = rv[3];
#undef ADD4
}

// ---------------------------------------------------------------- K3: exact distinct count per column
// v4: atomic-free race-tolerant multi-level dedup.
//   level: pending keys do plain LDS store tab[h]=key; barrier; read back.
//     read == own key  → value claimed this level (all duplicate copies agree)
//     read != own key  → lost the race to a different value → rehash, next level
//   count += non-empty slots (scan also clears table for the next level).
//   Each contended slot resolves ≥1 distinct value per level → guaranteed termination;
//   at load 0.5 the loser fraction is ~20% → ~3-4 levels for random data.
//   2 plain LDS ops per key per level, no CAS, no probe-loop scaffolding.
__global__ __launch_bounds__(256) void k_uniq(const unsigned* __restrict__ XT,
                                              unsigned* __restrict__ uniq) {
  __shared__ unsigned tab[8192];   // 32,768 B exactly → 5 blocks/CU
  const int t = threadIdx.x;
  const size_t base = (size_t)blockIdx.x * NN;

  // issue global loads first so they overlap table init
  const uint4* Xv = (const uint4*)(XT + base);
  uint4 kv0 = Xv[t], kv1 = Xv[256 + t], kv2 = Xv[512 + t], kv3 = Xv[768 + t];

  uint4* tv = (uint4*)tab;
  const uint4 e4 = make_uint4(EMPTYK, EMPTYK, EMPTYK, EMPTYK);
#pragma unroll
  for (int i = 0; i < 8; ++i) tv[t + 256 * i] = e4;

  unsigned key[16] = {kv0.x, kv0.y, kv0.z, kv0.w, kv1.x, kv1.y, kv1.z, kv1.w,
                      kv2.x, kv2.y, kv2.z, kv2.w, kv3.x, kv3.y, kv3.z, kv3.w};
  unsigned h[16];
#pragma unroll
  for (int q = 0; q < 16; ++q) h[q] = (key[q] * 2654435761u) >> 19;  // 13 bits
  unsigned pend = 0xFFFFu;
  unsigned salt = 0x9E3779B9u;
  int cnt = 0;
  __syncthreads();

  while (true) {
    // write pass (plain stores; racing word-writes resolve to one winner value)
#pragma unroll
    for (int q = 0; q < 16; ++q)
      if (pend & (1u << q)) tab[h[q]] = key[q];
    __syncthreads();
    // read-back classify
#pragma unroll
    for (int q = 0; q < 16; ++q)
      if (pend & (1u << q)) {
        if (tab[h[q]] == key[q]) pend &= ~(1u << q);
        else h[q] = ((key[q] ^ salt) * 2654435761u) >> 19;  // fresh hash next level
      }
    salt += 0x9E3779B9u;
    __syncthreads();                 // all classify-reads done before clearing
    // scan: count slots claimed this level, clear for next level
#pragma unroll
    for (int i = 0; i < 8; ++i) {
      uint4 v = tv[t + 256 * i];
      cnt += (v.x != EMPTYK) + (v.y != EMPTYK) + (v.z != EMPTYK) + (v.w != EMPTYK);
      tv[t + 256 * i] = e4;
    }
    if (__syncthreads_count(pend != 0) == 0) break;  // also orders clear before next write
  }

  for (int off = 32; off; off >>= 1) cnt += __shfl_down(cnt, off, 64);
  __syncthreads();                  // table idle; reuse for cross-wave partials
  if ((t & 63) == 0) tab[t >> 6] = (unsigned)cnt;
  __syncthreads();
  if (t == 0) uniq[blockIdx.x] = tab[0] + tab[1] + tab[2] + tab[3];
}

// ---------------------------------------------------------------- K2: reduce partials → 6 stats
__global__ void k_finalize(const float* __restrict__ P, const int* __restrict__ counts,
                           const unsigned* __restrict__ uniq, float* __restrict__ stats6) {
  const int col = blockIdx.x * 256 + threadIdx.x;  // 16384 columns
  const int b = col >> 8;
  const int f = col & 255;
  float acc[16];
#pragma unroll
  for (int i = 0; i < 16; ++i) acc[i] = 0.f;
  for (int sp = 0; sp < NSPLIT; ++sp) {
    const float4* p4 = (const float4*)(P + ((size_t)(b * NSPLIT + sp) * NF + f) * 16);
    float4 A = p4[0], B4 = p4[1], C4 = p4[2], D4 = p4[3];
    acc[0] += A.x; acc[1] += A.y; acc[2] += A.z; acc[3] = fmaxf(acc[3], A.w);
    acc[4] += B4.x; acc[5] += B4.y; acc[6] += B4.z; acc[7] += B4.w;
    acc[8] += C4.x; acc[9] += C4.y; acc[10] += C4.z; acc[11] += C4.w;
    acc[12] += D4.x; acc[13] += D4.y; acc[14] += D4.z;
  }
  const float invN = 1.f / (float)NN;
  const float mean = acc[0] * invN;
  float var = acc[1] * invN - mean * mean;
  if (var < 0.f) var = 0.f;
  const float meanabs = acc[2] * invN;
  const float maxabs = acc[3];
  const float miss = acc[4] * invN;
  const float uratio = (float)uniq[col] * invN;
  float btw = 0.f;
#pragma unroll
  for (int c = 0; c < NC; ++c) {
    float cntc = (float)counts[b * NC + c];
    float m = acc[5 + c] / fmaxf(cntc, 1.f);
    float d = m - mean;
    btw = fmaf(cntc * d, d, btw);
  }
  btw *= invN;  // counts.sum() == N
  const float target = btw / fmaxf(var, 1e-6f);
  float st[6] = {target, miss, uratio, var, meanabs, maxabs};
#pragma unroll
  for (int i = 0; i < 6; ++i)
    if (!(fabsf(st[i]) <= 3.4028235e38f)) st[i] = 0.f;  // nan_to_num(nan/±inf → 0)
#pragma unroll
  for (int i = 0; i < 6; ++i) stats6[(size_t)col * 6 + i] = st[i];
}

// ---------------------------------------------------------------- K4: MLP  gelu(stats@W1+b1)@W2+b2
__global__ __launch_bounds__(256) void k_mlp(const float* __restrict__ stats6,
                                             const float* __restrict__ W1,
                                             const float* __restrict__ b1,
                                             const float* __restrict__ W2,
                                             const float* __restrict__ b2,
                                             float* __restrict__ out) {
  __shared__ float w1s[6 * 64];
  __shared__ float b1s[64];
  __shared__ float w2s[64 * 128];
  __shared__ float b2s[128];
  __shared__ float sts[32 * 6];
  __shared__ float hs[64 * 36];  // pitch 36 keeps float4 reads 16B-aligned
  const int t = threadIdx.x;
  const int cb0 = blockIdx.x * 32;
  for (int i = t; i < 96; i += 256) ((float4*)w1s)[i] = ((const float4*)W1)[i];
  if (t < 64) b1s[t] = b1[t];
  for (int i = t; i < 2048; i += 256) ((float4*)w2s)[i] = ((const float4*)W2)[i];
  if (t < 128) b2s[t] = b2[t];
  if (t < 48) ((float4*)sts)[t] = ((const float4*)(stats6 + (size_t)cb0 * 6))[t];
  __syncthreads();

  const int k = t & 63, cg = t >> 6;
#pragma unroll
  for (int cc = 0; cc < 8; ++cc) {
    const int col = cg + 4 * cc;
    float pre = b1s[k];
#pragma unroll
    for (int s = 0; s < 6; ++s) pre = fmaf(sts[col * 6 + s], w1s[s * 64 + k], pre);
    const float h = 0.5f * pre * (1.f + erff(pre * 0.70710678118654752f));  // exact gelu
    hs[k * 36 + col] = h;
  }
  __syncthreads();

  const int j4 = (t & 31) * 4, c4 = (t >> 5) * 4;
  float4 a[4];
  const float4 bj = *(const float4*)&b2s[j4];
  a[0] = bj; a[1] = bj; a[2] = bj; a[3] = bj;
  for (int kk = 0; kk < 64; ++kk) {
    const float4 wv = *(const float4*)&w2s[kk * 128 + j4];
    const float4 hv = *(const float4*)&hs[kk * 36 + c4];
    const float hc[4] = {hv.x, hv.y, hv.z, hv.w};
#pragma unroll
    for (int ci = 0; ci < 4; ++ci) {
      a[ci].x = fmaf(hc[ci], wv.x, a[ci].x);
      a[ci].y = fmaf(hc[ci], wv.y, a[ci].y);
      a[ci].z = fmaf(hc[ci], wv.z, a[ci].z);
      a[ci].w = fmaf(hc[ci], wv.w, a[ci].w);
    }
  }
#pragma unroll
  for (int ci = 0; ci < 4; ++ci) {
    const int col = cb0 + c4 + ci;
    *(float4*)&out[(size_t)col * 128 + j4] = a[ci];
  }
}

// ---------------------------------------------------------------- launch
extern "C" void kernel_launch(void* const* d_in, const int* in_sizes, int n_in,
                              void* d_out, int out_size, void* d_ws, size_t ws_size,
                              hipStream_t stream) {
  const float* X = (const float*)d_in[0];
  const int* Y = (const int*)d_in[1];
  const float* W1 = (const float*)d_in[2];
  const float* b1 = (const float*)d_in[3];
  const float* W2 = (const float*)d_in[4];
  const float* b2 = (const float*)d_in[5];
  float* out = (float*)d_out;

  // workspace layout (needs ~272.4 MiB)
  char* w = (char*)d_ws;
  unsigned* XT = (unsigned*)w;                          // 268,435,456 B  [B,F,N] cleaned bit patterns
  float* P = (float*)(w + 268435456ull);                //  16,777,216 B  partial stats [B,S,F,16]
  float* stats6 = (float*)(w + 285212672ull);           //     393,216 B  [16384,6]
  int* counts = (int*)(w + 285605888ull);               //       2,560 B  [B,10]
  unsigned* uniq = (unsigned*)(w + 285608448ull);       //      65,536 B  [16384]

  k_counts<<<NB, 256, 0, stream>>>(Y, counts);
  k_stats<<<NB * NSPLIT, 256, 0, stream>>>(X, Y, XT, P);
  k_uniq<<<NB * NF, 256, 0, stream>>>(XT, uniq);
  k_finalize<<<64, 256, 0, stream>>>(P, counts, uniq, stats6);
  k_mlp<<<512, 256, 0, stream>>>(stats6, W1, b1, W2, b2, out);
}